// Round 4
// baseline (581.435 us; speedup 1.0000x reference)
//
#include <hip/hip_runtime.h>
#include <hip/hip_bf16.h>

// RNN: h_t = tanh(x_t U + h_{t-1} W + b), return h_T.  B=256 T=512 D=K=256.
// Phase 0: transpose U -> Ut fp16 [256][264] in ws.
// Phase 1: xU+b as fp16, layout [B][T][K] (m = b*512+t).  (unchanged control)
// Phase 2: 16 blocks x 16 batch rows, SIXTEEN waves (16 cols/wave) = 4 waves/SIMD.
//          Scan is latency-bound (r2/r3 evidence): doubling TLP fills the
//          ds_read->MFMA->tanh->ds_write chain gaps.  LDS read traffic doubles
//          (each wave reads the full 8KB h tile) -- deliberate bet that LDS BW
//          is not binding.  Per-wave: W B-frags 32 VGPR, 8 MFMAs as 2x4-deep
//          partials, 4 tanh.  lds_barrier (lgkmcnt-only) keeps xu ring in flight.

typedef _Float16 half8_t __attribute__((ext_vector_type(8)));
typedef _Float16 half2_t __attribute__((ext_vector_type(2)));
typedef float    float4_t __attribute__((ext_vector_type(4)));

#define MFMA16(a, b, c) __builtin_amdgcn_mfma_f32_16x16x32_f16((a), (b), (c), 0, 0, 0)

__device__ __forceinline__ half2_t pk_h2(float a, float b) {
    auto r = __builtin_amdgcn_cvt_pkrtz(a, b);
    return __builtin_bit_cast(half2_t, r);
}

__device__ __forceinline__ float fast_tanh(float x) {
    // tanh(x) = 1 - 2/(exp2(2*log2e*x)+1); overflow -> 1, underflow -> -1. OK.
    float e = __builtin_amdgcn_exp2f(2.8853900817779268f * x);
    return 1.0f - 2.0f * __builtin_amdgcn_rcpf(e + 1.0f);
}

// LDS-only barrier: order h dbuf write->read WITHOUT draining vmem prefetches.
__device__ __forceinline__ void lds_barrier() {
    __builtin_amdgcn_sched_barrier(0);
    asm volatile("s_waitcnt lgkmcnt(0)" ::: "memory");
    __builtin_amdgcn_s_barrier();
    __builtin_amdgcn_sched_barrier(0);
}

// ---------------- Phase 0: U[d][n] fp32 -> Ut[n][d] fp16 (row stride 264) ----------
__global__ void transpose_u(const float* __restrict__ U, _Float16* __restrict__ Ut) {
    int id = blockIdx.x * 256 + threadIdx.x;   // 65536 elements
    int d = id >> 8, n = id & 255;
    Ut[n * 264 + d] = (_Float16)U[id];
}

// ---------------- Phase 1: xU GEMM, 128x256 tile, BK=32, dbuf LDS ------------------
// grid 1024: m0 = bx*128, m = b*512 + t (natural x row order). A reads contiguous.
__global__ __launch_bounds__(256, 2) void xu_gemm(
    const float* __restrict__ x,        // [B*T][256] fp32  (m = b*512+t)
    const _Float16* __restrict__ Ut,    // [256][264] fp16
    const float* __restrict__ bias,     // [256]
    half2_t* __restrict__ xu)           // [B*T][128] half2 (= [B*T][256] halves)
{
    __shared__ char lds[61440];  // As[2][128*80B] @0, Bs[2][256*80B] @20480
    const int tid = threadIdx.x;
    const int lane = tid & 63, w = tid >> 6, l15 = lane & 15, q = lane >> 4;
    const int bx = blockIdx.x;
    const size_t m0 = (size_t)bx * 128;

    float4 ar[4];
    uint4  br[4];

    auto loadA = [&](int it) {
#pragma unroll
        for (int i = 0; i < 4; ++i) {
            int u = tid + 256 * i, row = u >> 3, seg = u & 7;
            ar[i] = *(const float4*)(x + (m0 + row) * 256 + it * 32 + seg * 4);
        }
    };
    auto loadB = [&](int it) {
#pragma unroll
        for (int i = 0; i < 4; ++i) {
            int u = tid + 256 * i, p = u >> 2, seg = u & 3;
            int c = 32 * (p >> 5) + 2 * (p & 15) + ((p >> 4) & 1);
            br[i] = *(const uint4*)((const char*)Ut + c * 528 + it * 64 + seg * 16);
        }
    };
    auto writeAB = [&](int s) {
        char* As = lds + s * 10240;
        char* Bs = lds + 20480 + s * 20480;
#pragma unroll
        for (int i = 0; i < 4; ++i) {
            int u = tid + 256 * i, row = u >> 3, seg = u & 7;
            half2_t p0 = pk_h2(ar[i].x, ar[i].y);
            half2_t p1 = pk_h2(ar[i].z, ar[i].w);
            uint2 v;
            v.x = __builtin_bit_cast(unsigned, p0);
            v.y = __builtin_bit_cast(unsigned, p1);
            *(uint2*)(As + row * 80 + seg * 8) = v;
        }
#pragma unroll
        for (int i = 0; i < 4; ++i) {
            int u = tid + 256 * i, p = u >> 2, seg = u & 3;
            *(uint4*)(Bs + p * 80 + seg * 16) = br[i];
        }
    };

    float4_t acc[32];
#pragma unroll
    for (int i = 0; i < 32; ++i) { acc[i][0] = 0.f; acc[i][1] = 0.f; acc[i][2] = 0.f; acc[i][3] = 0.f; }

    loadA(0); loadB(0); writeAB(0);
    __syncthreads();

    for (int it = 0; it < 8; ++it) {
        if (it < 7) { loadA(it + 1); loadB(it + 1); }
        const char* As = lds + (it & 1) * 10240;
        const char* Bs = lds + 20480 + (it & 1) * 20480;
        half8_t af[2];
#pragma unroll
        for (int ms = 0; ms < 2; ++ms)
            af[ms] = *(const half8_t*)(As + (32 * w + 16 * ms + l15) * 80 + q * 16);
#pragma unroll
        for (int ns = 0; ns < 16; ++ns) {
            half8_t bf = *(const half8_t*)(Bs + (16 * ns + l15) * 80 + q * 16);
            acc[ns * 2 + 0] = MFMA16(af[0], bf, acc[ns * 2 + 0]);
            acc[ns * 2 + 1] = MFMA16(af[1], bf, acc[ns * 2 + 1]);
        }
        if (it < 7) writeAB((it + 1) & 1);
        __syncthreads();
    }

    // epilogue: add bias (reference folds b into xU), pack col pairs
#pragma unroll
    for (int ms = 0; ms < 2; ++ms)
#pragma unroll
        for (int j = 0; j < 8; ++j) {
            const int c = 32 * j + 2 * l15;
            const float2 bb = *(const float2*)(bias + c);
#pragma unroll
            for (int i = 0; i < 4; ++i) {
                float v0 = acc[(2 * j) * 2 + ms][i] + bb.x;
                float v1 = acc[(2 * j + 1) * 2 + ms][i] + bb.y;
                half2_t p = pk_h2(v0, v1);
                int m_g = bx * 128 + 32 * w + 16 * ms + q * 4 + i;
                xu[(size_t)m_g * 128 + (c >> 1)] = p;
            }
        }
}

// ---------------- Phase 2: 512-step scan, 16 waves, W stationary in VGPRs ----------
// 16 blocks x 1024 threads (16 waves, 4/SIMD). Wave w owns cols [16w,16w+16) as
// ONE natural 16-wide tile: lane l15 <-> col 16w+l15.
__global__ __launch_bounds__(1024, 4) void rnn_scan(
    const _Float16* __restrict__ xu,    // [B*T][256] fp16 flat (m = b*512+t, bias folded)
    const float* __restrict__ W,        // [256][256] fp32
    float* __restrict__ out)            // [256][256] fp32
{
    __shared__ char lds[16896];         // h dbuf: 2 x (16 rows x 528B: 256 f16 + 8 pad)
    const int tid = threadIdx.x;
    const int lane = tid & 63, w = tid >> 6, l15 = lane & 15, q = lane >> 4;
    const int blk = blockIdx.x;         // 0..15 -> rows 16*blk..+15
    const int c = 16 * w + l15;         // this lane's output column

    // one-time: W -> B-frags in registers. wf[c8]: k = 32*c8 + 8q + j, col = c.
    half8_t wf[8];
#pragma unroll
    for (int c8 = 0; c8 < 8; ++c8) {
        half8_t f;
#pragma unroll
        for (int j = 0; j < 8; ++j) {
            int k = 32 * c8 + q * 8 + j;
            f[j] = (_Float16)W[k * 256 + c];
        }
        wf[c8] = f;
    }

    // h0 = 0 (both buffers)
    for (int i = tid; i < 16896 / 4; i += 1024) ((int*)lds)[i] = 0;

    const int rowg0 = 16 * blk + q * 4;          // + i gives this lane's C rows

    // 4-deep prefetch ring for xU (statically indexed; stays in VGPRs)
    _Float16 xr[4][4];
#pragma unroll
    for (int p = 0; p < 4; ++p)
#pragma unroll
        for (int i = 0; i < 4; ++i)
            xr[p][i] = xu[((size_t)(rowg0 + i) * 512 + p) * 256 + c];

    __syncthreads();

    char* const hbuf0 = (char*)lds;
    char* const hbuf1 = (char*)lds + 8448;

    for (int t4 = 0; t4 < 512; t4 += 4) {
#pragma unroll
        for (int p = 0; p < 4; ++p) {
            const int t = t4 + p;

            // this step's h from LDS (A-frags; critical-path head, issue first)
            const char* hcur = (t & 1) ? hbuf1 : hbuf0;
            half8_t af[8];
#pragma unroll
            for (int c8 = 0; c8 < 8; ++c8)
                af[c8] = *(const half8_t*)(hcur + l15 * 528 + c8 * 64 + q * 16);

            // acc init from xU (bias folded); two 4-deep partial chains
            float4_t aA, aB;
#pragma unroll
            for (int i = 0; i < 4; ++i) { aA[i] = (float)xr[p][i]; aB[i] = 0.f; }

            // prefetch xU for t+4 (survives the raw barrier; consumed 4 steps on)
            const int tn = (t + 4 <= 511) ? (t + 4) : 511;
#pragma unroll
            for (int i = 0; i < 4; ++i)
                xr[p][i] = xu[((size_t)(rowg0 + i) * 512 + tn) * 256 + c];

            // two interleaved 4-deep accumulation chains
#pragma unroll
            for (int c8 = 0; c8 < 4; ++c8) {
                aA = MFMA16(af[2 * c8],     wf[2 * c8],     aA);
                aB = MFMA16(af[2 * c8 + 1], wf[2 * c8 + 1], aB);
            }

            if (t == 511) {
#pragma unroll
                for (int i = 0; i < 4; ++i)
                    out[(rowg0 + i) * 256 + c] = fast_tanh(aA[i] + aB[i]);
            } else {
                char* hnext = ((t + 1) & 1) ? hbuf1 : hbuf0;
#pragma unroll
                for (int i = 0; i < 4; ++i) {
                    float v = fast_tanh(aA[i] + aB[i]);
                    *(_Float16*)(hnext + (q * 4 + i) * 528 + c * 2) = (_Float16)v;
                }
            }
            // LDS-only barrier: does NOT drain vmcnt (prefetch stays in flight)
            lds_barrier();
        }
    }
}

extern "C" void kernel_launch(void* const* d_in, const int* in_sizes, int n_in,
                              void* d_out, int out_size, void* d_ws, size_t ws_size,
                              hipStream_t stream) {
    const float* x = (const float*)d_in[0];   // [256,512,256]
    const float* U = (const float*)d_in[1];   // [256,256]
    const float* W = (const float*)d_in[2];   // [256,256]
    const float* b = (const float*)d_in[3];   // [256]
    float* out = (float*)d_out;

    char* ws = (char*)d_ws;
    _Float16* Ut = (_Float16*)ws;                       // 256*264*2 = 135168 B
    half2_t*  xu = (half2_t*)(ws + 262144);             // 512*256*256*2 = 67,108,864 B
    // requires ws_size >= 67,371,008 B

    transpose_u<<<256, 256, 0, stream>>>(U, Ut);
    xu_gemm<<<1024, 256, 0, stream>>>(x, Ut, b, xu);
    rnn_scan<<<16, 1024, 0, stream>>>((const _Float16*)xu, W, out);
}

// Round 6
// 519.948 us; speedup vs baseline: 1.1183x; 1.1183x over previous
//
#include <hip/hip_runtime.h>
#include <hip/hip_bf16.h>

// RNN: h_t = tanh(x_t U + h_{t-1} W + b), return h_T.  B=256 T=512 D=K=256.
// Phase 0: transpose U -> Ut fp16 [256][264] in ws.
// Phase 1: xU+b as fp16, layout [B][T][K] (m = b*512+t).  (unchanged control)
// Phase 2: r3 structure (16 blocks x 8 waves x 32 cols, W in VGPRs, lds_barrier)
//          with VALU stripped off the critical loop:
//          - xu prefetch via 32-bit offsets marching +128/step; last 4 steps
//            peeled so no clamp and no per-step t==511 branch
//          - ds addressing = per-lane base + imm offsets; dbuf parity compile-time
//          ORDER INVARIANT (r5 bug fix): ring slot t&3 is consumed into acc
//          registers BEFORE the t+4 prefetch overwrites it.

typedef _Float16 half8_t __attribute__((ext_vector_type(8)));
typedef _Float16 half2_t __attribute__((ext_vector_type(2)));
typedef float    float4_t __attribute__((ext_vector_type(4)));

#define MFMA16(a, b, c) __builtin_amdgcn_mfma_f32_16x16x32_f16((a), (b), (c), 0, 0, 0)

__device__ __forceinline__ half2_t pk_h2(float a, float b) {
    auto r = __builtin_amdgcn_cvt_pkrtz(a, b);
    return __builtin_bit_cast(half2_t, r);
}

__device__ __forceinline__ float fast_tanh(float x) {
    // tanh(x) = 1 - 2/(exp2(2*log2e*x)+1); overflow -> 1, underflow -> -1. OK.
    float e = __builtin_amdgcn_exp2f(2.8853900817779268f * x);
    return 1.0f - 2.0f * __builtin_amdgcn_rcpf(e + 1.0f);
}

// LDS-only barrier: order h dbuf write->read WITHOUT draining vmem prefetches.
__device__ __forceinline__ void lds_barrier() {
    __builtin_amdgcn_sched_barrier(0);
    asm volatile("s_waitcnt lgkmcnt(0)" ::: "memory");
    __builtin_amdgcn_s_barrier();
    __builtin_amdgcn_sched_barrier(0);
}

// ---------------- Phase 0: U[d][n] fp32 -> Ut[n][d] fp16 (row stride 264) ----------
__global__ void transpose_u(const float* __restrict__ U, _Float16* __restrict__ Ut) {
    int id = blockIdx.x * 256 + threadIdx.x;   // 65536 elements
    int d = id >> 8, n = id & 255;
    Ut[n * 264 + d] = (_Float16)U[id];
}

// ---------------- Phase 1: xU GEMM, 128x256 tile, BK=32, dbuf LDS ------------------
// grid 1024: m0 = bx*128, m = b*512 + t (natural x row order). A reads contiguous.
__global__ __launch_bounds__(256, 2) void xu_gemm(
    const float* __restrict__ x,        // [B*T][256] fp32  (m = b*512+t)
    const _Float16* __restrict__ Ut,    // [256][264] fp16
    const float* __restrict__ bias,     // [256]
    half2_t* __restrict__ xu)           // [B*T][128] half2 (= [B*T][256] halves)
{
    __shared__ char lds[61440];  // As[2][128*80B] @0, Bs[2][256*80B] @20480
    const int tid = threadIdx.x;
    const int lane = tid & 63, w = tid >> 6, l15 = lane & 15, q = lane >> 4;
    const int bx = blockIdx.x;
    const size_t m0 = (size_t)bx * 128;

    float4 ar[4];
    uint4  br[4];

    auto loadA = [&](int it) {
#pragma unroll
        for (int i = 0; i < 4; ++i) {
            int u = tid + 256 * i, row = u >> 3, seg = u & 7;
            ar[i] = *(const float4*)(x + (m0 + row) * 256 + it * 32 + seg * 4);
        }
    };
    auto loadB = [&](int it) {
#pragma unroll
        for (int i = 0; i < 4; ++i) {
            int u = tid + 256 * i, p = u >> 2, seg = u & 3;
            int c = 32 * (p >> 5) + 2 * (p & 15) + ((p >> 4) & 1);
            br[i] = *(const uint4*)((const char*)Ut + c * 528 + it * 64 + seg * 16);
        }
    };
    auto writeAB = [&](int s) {
        char* As = lds + s * 10240;
        char* Bs = lds + 20480 + s * 20480;
#pragma unroll
        for (int i = 0; i < 4; ++i) {
            int u = tid + 256 * i, row = u >> 3, seg = u & 7;
            half2_t p0 = pk_h2(ar[i].x, ar[i].y);
            half2_t p1 = pk_h2(ar[i].z, ar[i].w);
            uint2 v;
            v.x = __builtin_bit_cast(unsigned, p0);
            v.y = __builtin_bit_cast(unsigned, p1);
            *(uint2*)(As + row * 80 + seg * 8) = v;
        }
#pragma unroll
        for (int i = 0; i < 4; ++i) {
            int u = tid + 256 * i, p = u >> 2, seg = u & 3;
            *(uint4*)(Bs + p * 80 + seg * 16) = br[i];
        }
    };

    float4_t acc[32];
#pragma unroll
    for (int i = 0; i < 32; ++i) { acc[i][0] = 0.f; acc[i][1] = 0.f; acc[i][2] = 0.f; acc[i][3] = 0.f; }

    loadA(0); loadB(0); writeAB(0);
    __syncthreads();

    for (int it = 0; it < 8; ++it) {
        if (it < 7) { loadA(it + 1); loadB(it + 1); }
        const char* As = lds + (it & 1) * 10240;
        const char* Bs = lds + 20480 + (it & 1) * 20480;
        half8_t af[2];
#pragma unroll
        for (int ms = 0; ms < 2; ++ms)
            af[ms] = *(const half8_t*)(As + (32 * w + 16 * ms + l15) * 80 + q * 16);
#pragma unroll
        for (int ns = 0; ns < 16; ++ns) {
            half8_t bf = *(const half8_t*)(Bs + (16 * ns + l15) * 80 + q * 16);
            acc[ns * 2 + 0] = MFMA16(af[0], bf, acc[ns * 2 + 0]);
            acc[ns * 2 + 1] = MFMA16(af[1], bf, acc[ns * 2 + 1]);
        }
        if (it < 7) writeAB((it + 1) & 1);
        __syncthreads();
    }

    // epilogue: add bias (reference folds b into xU), pack col pairs
#pragma unroll
    for (int ms = 0; ms < 2; ++ms)
#pragma unroll
        for (int j = 0; j < 8; ++j) {
            const int c = 32 * j + 2 * l15;
            const float2 bb = *(const float2*)(bias + c);
#pragma unroll
            for (int i = 0; i < 4; ++i) {
                float v0 = acc[(2 * j) * 2 + ms][i] + bb.x;
                float v1 = acc[(2 * j + 1) * 2 + ms][i] + bb.y;
                half2_t p = pk_h2(v0, v1);
                int m_g = bx * 128 + 32 * w + 16 * ms + q * 4 + i;
                xu[(size_t)m_g * 128 + (c >> 1)] = p;
            }
        }
}

// ---------------- Phase 2: 512-step scan, 8 waves, W stationary in VGPRs -----------
// 16 blocks x 512 threads. Wave w owns cols [32w,32w+32) as two column-
// interleaved 16-wide tiles (cols 32w+2l and 32w+2l+1).
__global__ __launch_bounds__(512, 2) void rnn_scan(
    const half2_t* __restrict__ xu,     // [B*T][128] half2 (m = b*512+t, bias folded)
    const float* __restrict__ W,        // [256][256] fp32
    float* __restrict__ out)            // [256][256] fp32
{
    __shared__ char lds[16896];         // h dbuf: 2 x (16 rows x 528B: 256 f16 + 8 pad)
    const int tid = threadIdx.x;
    const int lane = tid & 63, w = tid >> 6, l15 = lane & 15, q = lane >> 4;
    const int blk = blockIdx.x;         // 0..15 -> rows 16*blk..+15
    const int c0 = 32 * w + 2 * l15;    // even column of this lane's tile pair

    // one-time: W -> B-frags in registers (each (k,col) loaded by exactly one lane)
    half8_t wf[2][8];
#pragma unroll
    for (int tt = 0; tt < 2; ++tt)
#pragma unroll
        for (int c = 0; c < 8; ++c) {
            half8_t f;
#pragma unroll
            for (int j = 0; j < 8; ++j) {
                int k = 32 * c + q * 8 + j;
                f[j] = (_Float16)W[k * 256 + c0 + tt];
            }
            wf[tt][c] = f;
        }

    // h0 = 0
    for (int i = tid; i < 16896 / 4; i += 512) ((int*)lds)[i] = 0;

    const int rowg0 = 16 * blk + q * 4;          // + i gives this lane's C rows
    const int colh = c0 >> 1;

    // 32-bit element offsets for the xu stream, marching +128/step
    unsigned xoff[4];
#pragma unroll
    for (int i = 0; i < 4; ++i)
        xoff[i] = (unsigned)(rowg0 + i) * 512u * 128u + (unsigned)colh;

    // 4-deep prefetch ring (statically indexed; stays in VGPRs)
    half2_t xr[4][4];
#pragma unroll
    for (int p = 0; p < 4; ++p)
#pragma unroll
        for (int i = 0; i < 4; ++i)
            xr[p][i] = xu[xoff[i] + (unsigned)p * 128u];
#pragma unroll
    for (int i = 0; i < 4; ++i) xoff[i] += 4u * 128u;

    char* const L = (char*)lds;
    const int afb = l15 * 528 + q * 16;       // ds_read base; + c8*64 immediates
    const int hwb = (q * 4) * 528 + c0 * 2;   // ds_write base; + i*528 immediates

    __syncthreads();

    // One scan step. P_ = ring slot (t&3), PAR = t&1, DOPF = prefetch t+4,
    // LAST = t==511.  All compile-time at each expansion.
    // ORDER: af ds_read -> acc init CONSUMES xr[P_] -> prefetch OVERWRITES xr[P_].
#define SCAN_STEP(P_, PAR, DOPF, LAST)                                          \
    {                                                                           \
        const char* hcur = L + ((PAR) ? 8448 : 0);                              \
        half8_t af[8];                                                          \
        _Pragma("unroll")                                                       \
        for (int c8 = 0; c8 < 8; ++c8)                                          \
            af[c8] = *(const half8_t*)(hcur + afb + c8 * 64);                   \
        float4_t a0a, a1a, a0b, a1b;                                            \
        _Pragma("unroll")                                                       \
        for (int i = 0; i < 4; ++i) {                                           \
            a0a[i] = (float)xr[P_][i][0];                                       \
            a1a[i] = (float)xr[P_][i][1];                                       \
            a0b[i] = 0.f; a1b[i] = 0.f;                                         \
        }                                                                       \
        if (DOPF) {                                                             \
            _Pragma("unroll")                                                   \
            for (int i = 0; i < 4; ++i) {                                       \
                xr[P_][i] = xu[xoff[i]];                                        \
                xoff[i] += 128u;                                                \
            }                                                                   \
        }                                                                       \
        _Pragma("unroll")                                                       \
        for (int c = 0; c < 4; ++c) {                                           \
            a0a = MFMA16(af[2 * c],     wf[0][2 * c],     a0a);                 \
            a1a = MFMA16(af[2 * c],     wf[1][2 * c],     a1a);                 \
            a0b = MFMA16(af[2 * c + 1], wf[0][2 * c + 1], a0b);                 \
            a1b = MFMA16(af[2 * c + 1], wf[1][2 * c + 1], a1b);                 \
        }                                                                       \
        if (LAST) {                                                             \
            _Pragma("unroll")                                                   \
            for (int i = 0; i < 4; ++i) {                                       \
                float2 st;                                                      \
                st.x = fast_tanh(a0a[i] + a0b[i]);                              \
                st.y = fast_tanh(a1a[i] + a1b[i]);                              \
                *(float2*)(&out[(rowg0 + i) * 256 + c0]) = st;                  \
            }                                                                   \
        } else {                                                                \
            char* hnext = L + ((PAR) ? 0 : 8448);                               \
            _Pragma("unroll")                                                   \
            for (int i = 0; i < 4; ++i) {                                       \
                float v0 = fast_tanh(a0a[i] + a0b[i]);                          \
                float v1 = fast_tanh(a1a[i] + a1b[i]);                          \
                *(half2_t*)(hnext + hwb + i * 528) = pk_h2(v0, v1);             \
            }                                                                   \
            lds_barrier();                                                      \
        }                                                                       \
    }

    // main: t = 0..507; prefetch t+4 <= 511 always in-bounds, offsets march free
    for (int t4 = 0; t4 < 508; t4 += 4) {
        SCAN_STEP(0, 0, 1, 0)
        SCAN_STEP(1, 1, 1, 0)
        SCAN_STEP(2, 0, 1, 0)
        SCAN_STEP(3, 1, 1, 0)
    }
    // peeled tail t = 508..511: ring already holds xu[508..511]; no prefetch
    SCAN_STEP(0, 0, 0, 0)
    SCAN_STEP(1, 1, 0, 0)
    SCAN_STEP(2, 0, 0, 0)
    SCAN_STEP(3, 1, 0, 1)
#undef SCAN_STEP
}

extern "C" void kernel_launch(void* const* d_in, const int* in_sizes, int n_in,
                              void* d_out, int out_size, void* d_ws, size_t ws_size,
                              hipStream_t stream) {
    const float* x = (const float*)d_in[0];   // [256,512,256]
    const float* U = (const float*)d_in[1];   // [256,256]
    const float* W = (const float*)d_in[2];   // [256,256]
    const float* b = (const float*)d_in[3];   // [256]
    float* out = (float*)d_out;

    char* ws = (char*)d_ws;
    _Float16* Ut = (_Float16*)ws;                       // 256*264*2 = 135168 B
    half2_t*  xu = (half2_t*)(ws + 262144);             // 512*256*256*2 = 67,108,864 B
    // requires ws_size >= 67,371,008 B

    transpose_u<<<256, 256, 0, stream>>>(U, Ut);
    xu_gemm<<<1024, 256, 0, stream>>>(x, Ut, b, xu);
    rnn_scan<<<16, 512, 0, stream>>>(xu, W, out);
}